// Round 4
// baseline (408.403 us; speedup 1.0000x reference)
//
#include <hip/hip_runtime.h>
#include <math.h>

#define B_   16
#define O_   1024
#define M_   64
#define C_   32
#define INO  16
#define INA  8
#define SLOPE 0.2f

// per-block partials: 25 parity-split fields x 64 lanes
#define NPQ    1600
#define WS_CNT 0          // 64 int counters (zeroed by hipMemsetAsync each launch)
#define WS_PART 64        // float offset of partials (2048 * NPQ floats = 13.1 MB)

__device__ inline float rfl(float x) {
    return __int_as_float(__builtin_amdgcn_readfirstlane(__float_as_int(x)));
}

// async global->LDS, 16B/lane, NT cache policy (aux bit1) so the once-read
// arc streams do not churn L2/MALL; steady state becomes pure HBM streaming.
__device__ __forceinline__ void gl_lds16_nt(const float* g, float* l) {
    __builtin_amdgcn_global_load_lds(
        (const __attribute__((address_space(1))) void*)(g),
        (__attribute__((address_space(3))) void*)(l),
        16, 0, 2);
}

#define WAITV(N) do { asm volatile("s_waitcnt vmcnt(" #N ")" ::: "memory"); \
                      __builtin_amdgcn_sched_barrier(0); } while(0)
#define WAITL()  do { asm volatile("s_waitcnt lgkmcnt(0)" ::: "memory"); \
                      __builtin_amdgcn_sched_barrier(0); } while(0)

// ---------------- single fused kernel ----------------
// r3 post-mortem: delivered BW invariant across occupancy 14->40% and four
// load structures => CU-side is not the limit. This round: (1) NT arc loads
// (test the L3-mix service-rate theory), (2) absorb k_pre (redundant
// per-thread micro-GEMVs, VALU was 87% idle) and k_redfin (last-block-of-
// group finalize, agent-scope stores/loads + device counter) to remove two
// dispatches and two serialization gaps from the 207us total.
__global__ __launch_bounds__(256) void k_fused(
        const float* __restrict__ adj0, const float* __restrict__ adj1,
        const float* __restrict__ adj2, const float* __restrict__ adj3,
        const float* __restrict__ feat_opes,
        const float* __restrict__ feat_mas, const float* __restrict__ feat_buf,
        const float* __restrict__ fin_ma,  const float* __restrict__ fin_buf,
        const float* __restrict__ fout_ma, const float* __restrict__ fout_buf,
        const float* __restrict__ W_ope,  const float* __restrict__ W_mas,
        const float* __restrict__ W_buf,  const float* __restrict__ W_arc_in,
        const float* __restrict__ W_arc_out,
        const float* __restrict__ attn_ope, const float* __restrict__ attn_mas,
        const float* __restrict__ attn_arc,
        float* __restrict__ ws, float* __restrict__ out) {
    int tid = threadIdx.x;
    int l   = tid & 63;
    int p   = l & 1;                                  // k-half / field parity
    int y   = __builtin_amdgcn_readfirstlane(tid >> 6);

    int bid = blockIdx.x;                 // [0, 2048)
    int cq  = bid & 31;
    int h   = (bid >> 5) & 1;
    int b   = (bid >> 6) & (B_ - 1);
    int br  = bid >> 10;
    int g   = bid >> 5;                   // finalize group (br,b,h), 64 groups

    int m   = h*32 + (l >> 1);
    int o0  = cq*32 + y*8;

    const float* A_in  = br ? adj2 : adj0;
    const float* A_out = br ? adj3 : adj1;
    const float* fin   = br ? fin_buf  : fin_ma;
    const float* fout  = br ? fout_buf : fout_ma;
    const float* fnode = br ? feat_buf : feat_mas;
    const float* Wnode = br ? W_buf    : W_mas;

    __shared__ float smem[8192];          // staging (4w x 2KB) -> reduce -> finalize
    __shared__ float sflag;
    float* ST = smem + y*2048;

    const float* pi = fin  + ((size_t)(b*O_ + o0))*512 + h*256 + l*4;
    const float* po = fout + ((size_t)(b*O_ + o0))*512 + h*256 + l*4;

#define STAGE(IT) do { \
        float* _d = ST + (((IT) >> 1) & 1)*1024 + ((IT) & 1)*512; \
        gl_lds16_nt(pi + (IT)*512, _d); \
        gl_lds16_nt(po + (IT)*512, _d + 256); \
    } while(0)

    // issue the first 8 staged loads immediately; prologue compute hides them
    STAGE(0); STAGE(1); STAGE(2); STAGE(3);
    __builtin_amdgcn_sched_barrier(0);

    // ---- absorbed k_pre: per-thread redundant micro-GEMVs (VALU is idle) ----
    float wi4a[4] = {0,0,0,0}, wo4a[4] = {0,0,0,0};
    float wn8[8]  = {0,0,0,0,0,0,0,0};
#pragma unroll
    for (int c = 0; c < 32; c += 4) {
        float4 aa = *(const float4*)(attn_arc + c);
        float4 am = *(const float4*)(attn_mas + c);
#pragma unroll
        for (int j2 = 0; j2 < 4; ++j2) {
            float4 w1 = *(const float4*)(W_arc_in  + (4*p + j2)*32 + c);
            float4 w2 = *(const float4*)(W_arc_out + (4*p + j2)*32 + c);
            wi4a[j2] += w1.x*aa.x + w1.y*aa.y + w1.z*aa.z + w1.w*aa.w;
            wo4a[j2] += w2.x*aa.x + w2.y*aa.y + w2.z*aa.z + w2.w*aa.w;
        }
#pragma unroll
        for (int k = 0; k < 8; ++k) {
            float4 wk = *(const float4*)(Wnode + k*32 + c);
            wn8[k] += wk.x*am.x + wk.y*am.y + wk.z*am.z + wk.w*am.w;
        }
    }
    float wiA=wi4a[0], wiB=wi4a[1], wiC=wi4a[2], wiD=wi4a[3];
    float woA=wo4a[0], woB=wo4a[1], woC=wo4a[2], woD=wo4a[3];

    const float* fnr = fnode + (size_t)(b*M_ + m)*INA;
    float4 fn0 = *(const float4*)(fnr);
    float4 fn1 = *(const float4*)(fnr + 4);
    float e_node_m = fn0.x*wn8[0] + fn0.y*wn8[1] + fn0.z*wn8[2] + fn0.w*wn8[3]
                   + fn1.x*wn8[4] + fn1.y*wn8[5] + fn1.z*wn8[6] + fn1.w*wn8[7];

    float wo16[16];
#pragma unroll
    for (int j2 = 0; j2 < 16; ++j2) wo16[j2] = 0.f;
#pragma unroll
    for (int c = 0; c < 32; c += 4) {
        float4 ao = *(const float4*)(attn_ope + c);
#pragma unroll
        for (int j2 = 0; j2 < 16; ++j2) {
            float4 w1 = *(const float4*)(W_ope + j2*32 + c);
            wo16[j2] += w1.x*ao.x + w1.y*ao.y + w1.z*ao.z + w1.w*ao.w;
        }
    }
    const float* fob = feat_opes + (size_t)(b*O_ + o0)*INO;
    float eo[8];
#pragma unroll
    for (int i = 0; i < 8; ++i) {
        float s = 0.f;
#pragma unroll
        for (int j2 = 0; j2 < 16; j2 += 4) {
            float4 f4 = *(const float4*)(fob + i*INO + j2);
            s += f4.x*wo16[j2] + f4.y*wo16[j2+1] + f4.z*wo16[j2+2] + f4.w*wo16[j2+3];
        }
        eo[i] = s;
    }

    // per-lane adjacency -> bitmask
    const float* Ai = A_in  + o0*M_ + m;
    const float* Ao = A_out + o0*M_ + m;
    unsigned amA = 0, amB = 0;
#pragma unroll
    for (int i = 0; i < 8; ++i) {
        amA |= (Ai[i*M_] == 1.0f) ? (1u << i) : 0u;
        amB |= (Ao[i*M_] == 1.0f) ? (1u << i) : 0u;
    }

    // ---- staged main loop (r3 structure, counted vmcnt) ----
    float ai0 = 0.f, ai1 = 0.f, ai2 = 0.f, ai3 = 0.f;
    float s0 = 0.f, s1 = 0.f, s2 = 0.f, s3 = 0.f;
    float lsum = 0.f;
    float wiv[8], wov[8];

#define COMP(IT) do { \
        const float* _t = ST + (((IT) >> 1) & 1)*1024 + ((IT) & 1)*512; \
        float4 _i4 = *(const float4*)(_t + l*4); \
        float4 _u4 = *(const float4*)(_t + 256 + l*4); \
        float _einp = _i4.x*wiA + _i4.y*wiB + _i4.z*wiC + _i4.w*wiD; \
        float _eutp = _u4.x*woA + _u4.y*woB + _u4.z*woC + _u4.w*woD; \
        float _ein = _einp + __shfl_xor(_einp, 1); \
        float _eut = _eutp + __shfl_xor(_eutp, 1); \
        float _bs = eo[IT] + e_node_m; \
        float _si = _bs + _ein;  _si = _si > 0.f ? _si : SLOPE*_si; \
        float _so = _bs + _eut;  _so = _so > 0.f ? _so : SLOPE*_so; \
        float _wgi = ((amA >> (IT)) & 1u) ? __expf(_si) : 0.f; \
        float _wgo = ((amB >> (IT)) & 1u) ? __expf(_so) : 0.f; \
        wiv[IT] = _wgi; wov[IT] = _wgo; \
        ai0 += _wgi*_i4.x; ai1 += _wgi*_i4.y; ai2 += _wgi*_i4.z; ai3 += _wgi*_i4.w; \
        s0  += _u4.x;      s1  += _u4.y;      s2  += _u4.z;      s3  += _u4.w; \
        lsum += p ? _wgo : _wgi; \
    } while(0)

    WAITV(6); COMP(0);
    WAITV(4); COMP(1);
    WAITL();  STAGE(4); STAGE(5);
    WAITV(6); COMP(2);
    WAITV(4); COMP(3);
    WAITL();  STAGE(6); STAGE(7);
    WAITV(6); COMP(4);
    WAITV(4); COMP(5);
    WAITV(2); COMP(6);
    WAITV(0); COMP(7);

#undef STAGE
#undef COMP

    // deferred feat_opes-weighted sums (rows are L1-hot from the eo pass)
    float aoi[8], aoo[8];
#pragma unroll
    for (int j = 0; j < 8; ++j) { aoi[j] = 0.f; aoo[j] = 0.f; }
    const float* fo = fob + p*8;
#pragma unroll
    for (int it = 0; it < 8; ++it) {
        float4 f0 = *(const float4*)(fo + it*INO);
        float4 f1 = *(const float4*)(fo + it*INO + 4);
        float wgi = wiv[it], wgo = wov[it];
        aoi[0] += wgi*f0.x; aoi[1] += wgi*f0.y; aoi[2] += wgi*f0.z; aoi[3] += wgi*f0.w;
        aoi[4] += wgi*f1.x; aoi[5] += wgi*f1.y; aoi[6] += wgi*f1.z; aoi[7] += wgi*f1.w;
        aoo[0] += wgo*f0.x; aoo[1] += wgo*f0.y; aoo[2] += wgo*f0.z; aoo[3] += wgo*f0.w;
        aoo[4] += wgo*f1.x; aoo[5] += wgo*f1.y; aoo[6] += wgo*f1.z; aoo[7] += wgo*f1.w;
    }

    // pack parity-split state vector (25 fields per lane)
    float v[25];
    v[0] = lsum;
    v[1] = ai0; v[2] = ai1; v[3] = ai2; v[4] = ai3;
#pragma unroll
    for (int j = 0; j < 8; ++j) { v[5+j] = aoi[j]; v[13+j] = aoo[j]; }
    v[21] = s0; v[22] = s1; v[23] = s2; v[24] = s3;

    // intra-block additive reduction reusing smem
    __syncthreads();
    if (y > 0) {
#pragma unroll
        for (int q = 0; q < 25; ++q) smem[(y-1)*1600 + q*64 + l] = v[q];
    }
    __syncthreads();
    if (y == 0) {
#pragma unroll
        for (int q = 0; q < 25; ++q)
            v[q] += smem[q*64 + l] + smem[1600 + q*64 + l] + smem[3200 + q*64 + l];

        // agent-scope partial stores (visible cross-XCD), then group counter
        float* pp = ws + WS_PART + (size_t)bid*NPQ;
#pragma unroll
        for (int q = 0; q < 25; ++q)
            __hip_atomic_store(&pp[q*64 + l], v[q],
                               __ATOMIC_RELAXED, __HIP_MEMORY_SCOPE_AGENT);
        __threadfence();
        if (l == 0) {
            int old = __hip_atomic_fetch_add((int*)ws + g, 1,
                                             __ATOMIC_ACQ_REL, __HIP_MEMORY_SCOPE_AGENT);
            sflag = (old == 31) ? 1.f : 0.f;
        }
    }
    __syncthreads();
    if (sflag == 0.f) return;

    // ---- absorbed k_redfin: last block of the group finalizes (br,b,h) ----
    __threadfence();   // acquire side
    float* red2 = smem;            // [0..1599]
    float* sW   = smem + 1600;     // [0..1311]: W_ope|W_arc_in|W_arc_out|W_node|attn_mas
    float* cinv = smem + 2912;     // [0..95]
    __syncthreads();               // staging/reduce areas fully consumed

    for (int i = tid; i < 512; i += 256) sW[i] = W_ope[i];
    sW[512 + tid]  = W_arc_in[tid & 255];
    sW[768 + tid]  = 0.f;   // placeholder overwritten below (keep flow simple)
    if (tid < 256) { sW[512 + tid] = W_arc_in[tid]; sW[768 + tid] = W_arc_out[tid]; sW[1024 + tid] = Wnode[tid]; }
    if (tid < 32)  sW[1280 + tid] = attn_mas[tid];

    // 32-way reduction over the group's cq-blocks (agent-scope loads)
    const float* part = ws + WS_PART;
    for (int ot = tid; ot < NPQ; ot += 256) {
        float s = 0.f;
#pragma unroll
        for (int c2 = 0; c2 < 32; ++c2)
            s += __hip_atomic_load(&part[(size_t)(g*32 + c2)*NPQ + ot],
                                   __ATOMIC_RELAXED, __HIP_MEMORY_SCOPE_AGENT);
        red2[ot] = s;
    }
    __syncthreads();

    // per-column scalars
    if (tid < 32) {
        int j = tid;
        float w8[8];
#pragma unroll
        for (int k = 0; k < 8; ++k) {
            float s = 0.f;
#pragma unroll
            for (int c = 0; c < 32; ++c) s += sW[1024 + k*32 + c]*sW[1280 + c];
            w8[k] = s;
        }
        const float* fr = fnode + (size_t)(b*M_ + h*32 + j)*INA;
        float en = 0.f;
#pragma unroll
        for (int k = 0; k < 8; ++k) en += fr[k]*w8[k];
        float ekk = 2.f*en; ekk = ekk > 0.f ? ekk : SLOPE*ekk;
        float wkk = __expf(ekk);
        float li = red2[2*j], lo = red2[2*j + 1];
        float inv_i = 1.f/(li + wkk);
        float inv_o = 1.f/(lo + wkk);
        cinv[j*3 + 0] = inv_i;
        cinv[j*3 + 1] = inv_o;
        cinv[j*3 + 2] = wkk*inv_i + wkk*inv_o;
    }
    __syncthreads();

    // epilogue: 32 columns x 32 outputs; thread -> (j, 4 c's)
    {
        int j  = tid >> 3;
        int c0 = tid & 7;
        int col = (br*B_ + b)*M_ + h*32 + j;
        int l0 = 2*j, l1 = 2*j + 1;
        float inv_i = cinv[j*3 + 0], inv_o = cinv[j*3 + 1], akk = cinv[j*3 + 2];

        const float* fr = fnode + (size_t)(b*M_ + h*32 + j)*INA;
        float fr8[8];
#pragma unroll
        for (int k = 0; k < 8; ++k) fr8[k] = fr[k];

        float* op = out + (size_t)col*C_;
#pragma unroll
        for (int k = 0; k < 4; ++k) {
            int c = c0 + 8*k;
            float s_ai = 0.f, s_oi = 0.f, s_ao = 0.f, s_oo = 0.f, pnc = 0.f;
#pragma unroll
            for (int q = 0; q < 4; ++q) {
                s_ai += red2[(1+q)*64 + l0]*sW[512 + q*32 + c]
                      + red2[(1+q)*64 + l1]*sW[512 + (4+q)*32 + c];
                s_ao += red2[(21+q)*64 + l0]*sW[768 + q*32 + c]
                      + red2[(21+q)*64 + l1]*sW[768 + (4+q)*32 + c];
            }
#pragma unroll
            for (int q = 0; q < 8; ++q) {
                s_oi += red2[(5+q)*64 + l0]*sW[q*32 + c]
                      + red2[(5+q)*64 + l1]*sW[(8+q)*32 + c];
                s_oo += red2[(13+q)*64 + l0]*sW[q*32 + c]
                      + red2[(13+q)*64 + l1]*sW[(8+q)*32 + c];
                pnc  += fr8[q]*sW[1024 + q*32 + c];
            }
            float x = (s_ai + s_oi)*inv_i + s_ao + s_oo*inv_o + pnc*akk;
            op[c] = 1.f/(1.f + __expf(-x));
        }
    }
}

extern "C" void kernel_launch(void* const* d_in, const int* in_sizes, int n_in,
                              void* d_out, int out_size, void* d_ws, size_t ws_size,
                              hipStream_t stream) {
    const float* adj0 = (const float*)d_in[0];
    const float* adj1 = (const float*)d_in[1];
    const float* adj2 = (const float*)d_in[2];
    const float* adj3 = (const float*)d_in[3];
    // d_in[4] = batch_idxes (unused by the reference)
    const float* feat_opes       = (const float*)d_in[5];
    const float* feat_mas        = (const float*)d_in[6];
    const float* feat_buf        = (const float*)d_in[7];
    const float* feat_arc_ma_in  = (const float*)d_in[8];
    const float* feat_arc_buf_in = (const float*)d_in[9];
    const float* feat_arc_ma_out = (const float*)d_in[10];
    const float* feat_arc_buf_out= (const float*)d_in[11];
    const float* W_ope    = (const float*)d_in[12];
    const float* W_mas    = (const float*)d_in[13];
    const float* W_buf    = (const float*)d_in[14];
    const float* W_arc_in = (const float*)d_in[15];
    const float* W_arc_out= (const float*)d_in[16];
    const float* attn_ope = (const float*)d_in[17];
    const float* attn_mas = (const float*)d_in[18];
    const float* attn_arc = (const float*)d_in[19];

    float* ws  = (float*)d_ws;
    float* out = (float*)d_out;

    // workspace: 64 int counters + 13.1 MB partials (r2/r3 confirmed ws_size fits)
    if (ws_size < (size_t)(WS_PART + 2048*NPQ)*sizeof(float)) return;

    hipMemsetAsync(d_ws, 0, 64*sizeof(int), stream);
    k_fused<<<2048, 256, 0, stream>>>(adj0, adj1, adj2, adj3,
                                      feat_opes, feat_mas, feat_buf,
                                      feat_arc_ma_in, feat_arc_buf_in,
                                      feat_arc_ma_out, feat_arc_buf_out,
                                      W_ope, W_mas, W_buf, W_arc_in, W_arc_out,
                                      attn_ope, attn_mas, attn_arc,
                                      ws, out);
}

// Round 5
// 212.988 us; speedup vs baseline: 1.9175x; 1.9175x over previous
//
#include <hip/hip_runtime.h>
#include <math.h>

#define B_   16
#define O_   1024
#define M_   64
#define C_   32
#define INO  16
#define INA  8
#define SLOPE 0.2f

// per-block partials: 25 parity-split fields x 64 lanes
#define NPQ   1600
#define NCH   4              // sequential o-chunks (of 32) per block
#define NCQ8  8              // o super-groups: 8 x 128 rows
#define GRID  (2*B_*2*NCQ8)  // 512 blocks

// workspace layout (float offsets)
#define WS_EOPE   0
#define WS_ENODE  (WS_EOPE + B_*O_)              // 16384
#define WS_PNODE  (WS_ENODE + 2*B_*M_)           // 18432
#define WS_WARC   (WS_PNODE + 2*B_*M_*C_)        // 83968
#define WS_MASK   (WS_WARC + 16)                 // 83984 (8192 floats = 32 KB packed adj bits)
#define WS_PART   (WS_MASK + 8192)               // 92176 (GRID*NPQ floats = 3.3 MB)

__device__ inline float rfl(float x) {
    return __int_as_float(__builtin_amdgcn_readfirstlane(__float_as_int(x)));
}

// async global->LDS, 16B/lane, DEFAULT cache policy (aux=2 was a 5x regression in r4)
__device__ __forceinline__ void gl_lds16(const float* g, float* l) {
    __builtin_amdgcn_global_load_lds(
        (const __attribute__((address_space(1))) void*)(g),
        (__attribute__((address_space(3))) void*)(l),
        16, 0, 0);
}

#define WAITV(N) do { asm volatile("s_waitcnt vmcnt(" #N ")" ::: "memory"); \
                      __builtin_amdgcn_sched_barrier(0); } while(0)
#define WAITL()  do { asm volatile("s_waitcnt lgkmcnt(0)" ::: "memory"); \
                      __builtin_amdgcn_sched_barrier(0); } while(0)

// ---------------- kernel 0: precompute (e_ope, p_node/e_node, w_arc, adj bitmasks) ----------------
__global__ void k_pre(const float* __restrict__ adj0, const float* __restrict__ adj1,
                      const float* __restrict__ adj2, const float* __restrict__ adj3,
                      const float* __restrict__ feat_opes,
                      const float* __restrict__ feat_mas,
                      const float* __restrict__ feat_buf,
                      const float* __restrict__ W_ope,
                      const float* __restrict__ W_mas,
                      const float* __restrict__ W_buf,
                      const float* __restrict__ W_arc_in,
                      const float* __restrict__ W_arc_out,
                      const float* __restrict__ attn_ope,
                      const float* __restrict__ attn_mas,
                      const float* __restrict__ attn_arc,
                      float* __restrict__ ws) {
    int tid = threadIdx.x;
    int bid = blockIdx.x;
    if (bid < 64) {
        // e_ope[b,o] = feat_opes[b,o,:] . (W_ope @ attn_ope)
        __shared__ float wo[INO];
        if (tid < INO) {
            float s = 0.f;
            for (int c = 0; c < C_; ++c) s += W_ope[tid*C_ + c]*attn_ope[c];
            wo[tid] = s;
        }
        __syncthreads();
        int idx = bid*256 + tid;                 // [0, 16384)
        const float* f = feat_opes + idx*INO;
        float s = 0.f;
#pragma unroll
        for (int j = 0; j < INO; ++j) s += f[j]*wo[j];
        ws[WS_EOPE + idx] = s;
    } else if (bid < 72) {
        // p_node / e_node for both branches
        int idx = (bid - 64)*256 + tid;          // [0, 2048)
        int br  = idx >> 10;
        int rem = idx & 1023;
        const float* f = (br == 0 ? feat_mas : feat_buf) + rem*INA;
        const float* W = (br == 0 ? W_mas : W_buf);
        float f8[INA];
#pragma unroll
        for (int k = 0; k < INA; ++k) f8[k] = f[k];
        float e = 0.f;
        float* pn = ws + WS_PNODE + idx*C_;
        for (int c = 0; c < C_; ++c) {
            float s = 0.f;
#pragma unroll
            for (int k = 0; k < INA; ++k) s += f8[k]*W[k*C_ + c];
            pn[c] = s;
            e += s*attn_mas[c];
        }
        ws[WS_ENODE + idx] = e;
    } else if (bid == 72) {
        // w_arc_in/out 8-vectors: W_arc @ attn_arc
        if (tid < 16) {
            const float* W = (tid < 8) ? W_arc_in : W_arc_out;
            int k = tid & 7;
            float s = 0.f;
            for (int c = 0; c < C_; ++c) s += W[k*C_ + c]*attn_arc[c];
            ws[WS_WARC + tid] = s;
        }
    } else {
        // packed adjacency bitmasks: per (br,m) 64 uints = A bits[32] | B bits[32]
        // uint j4 covers o in [j4*32, j4*32+32), bit t <-> o = j4*32+t
        int idx = (bid - 73)*256 + tid;          // [0, 4096)
        int br  = idx >> 11;
        int rem = idx & 2047;
        int mm  = rem >> 5;
        int j4  = rem & 31;
        const float* Ai = br ? adj2 : adj0;
        const float* Ao = br ? adj3 : adj1;
        unsigned a = 0u, bm = 0u;
        for (int t = 0; t < 32; ++t) {
            int o = j4*32 + t;
            a  |= (Ai[o*M_ + mm] == 1.0f) ? (1u << t) : 0u;
            bm |= (Ao[o*M_ + mm] == 1.0f) ? (1u << t) : 0u;
        }
        unsigned* mp = (unsigned*)(ws + WS_MASK) + (br*M_ + mm)*64;
        mp[j4]      = a;
        mp[32 + j4] = bm;
    }
}

// ---------------- kernel A: main streaming pass (long-run streams) ----------------
// r0-r3 post-mortem: delivered BW ~2.7 TB/s invariant across 5 CU-side
// structures (reg pipelines, atomics vs stores, LDS staging w/ counted vmcnt,
// occupancy 14->40%). Only never-varied factor: stream topology -- 2048
// co-resident blocks = 16K concurrent 1KB-granule streams at 2KB stride.
// This round: 512 blocks, each walking a CONTIGUOUS 256KB span per tensor
// (4 sequential chunks of the proven r3 body; accumulators persist across
// chunks). Adjacency pre-packed to bitmasks so the staged loop's vmcnt
// stream contains only staging loads. No atomics, no NT hints (r4 lesson).
__global__ __launch_bounds__(256) void k_main(
        const float* __restrict__ feat_opes,
        const float* __restrict__ fin_ma,  const float* __restrict__ fin_buf,
        const float* __restrict__ fout_ma, const float* __restrict__ fout_buf,
        float* __restrict__ ws) {
    int tid = threadIdx.x;
    int l   = tid & 63;
    int p   = l & 1;                                  // k-half / field parity
    int y   = __builtin_amdgcn_readfirstlane(tid >> 6);

    int bid = blockIdx.x;                 // [0, 512)
    int cq8 = bid & (NCQ8 - 1);           // 128-row super-group
    int h   = (bid >> 3) & 1;             // m-half
    int b   = (bid >> 4) & (B_ - 1);
    int br  = bid >> 8;

    int m   = h*32 + (l >> 1);

    const float* fin   = br ? fin_buf  : fin_ma;
    const float* fout  = br ? fout_buf : fout_ma;

    // 32 KB: 4 waves x 2KB-float staging; reused for reduction afterwards
    __shared__ float smem[8192];
    float* ST = smem + y*2048;

    float e_node_m = ws[WS_ENODE + (br*B_ + b)*M_ + m];

    // per-parity 4-element weight slices
    const float* wv = ws + WS_WARC + 4*p;
    float wiA = wv[0], wiB = wv[1], wiC = wv[2], wiD = wv[3];
    float woA = wv[8], woB = wv[9], woC = wv[10], woD = wv[11];

    // packed adjacency for this block's 128-row span: one uint4 per matrix
    const uint4* mp4 = (const uint4*)((const unsigned*)(ws + WS_MASK) + (br*M_ + m)*64);
    uint4 mA = mp4[cq8];
    uint4 mB = mp4[8 + cq8];

    const float* pib = fin  + (size_t)b*O_*512 + h*256 + l*4;
    const float* pob = fout + (size_t)b*O_*512 + h*256 + l*4;

    float ai0 = 0.f, ai1 = 0.f, ai2 = 0.f, ai3 = 0.f;
    float s0 = 0.f, s1 = 0.f, s2 = 0.f, s3 = 0.f;
    float lsum = 0.f;
    float aoi[8], aoo[8];
#pragma unroll
    for (int j = 0; j < 8; ++j) { aoi[j] = 0.f; aoo[j] = 0.f; }

    // drain all prologue loads so vmcnt counts only staging ops
    asm volatile("s_waitcnt vmcnt(0)" ::: "memory");
    __builtin_amdgcn_sched_barrier(0);

#pragma unroll
    for (int ch = 0; ch < NCH; ++ch) {
        int o0 = cq8*128 + ch*32 + y*8;   // this wave: o in [o0, o0+8)
        const float* pi = pib + (size_t)o0*512;
        const float* po = pob + (size_t)o0*512;

        // wave-uniform e_ope -> SGPRs (drained before staging begins)
        const float* e_ope = ws + WS_EOPE + b*O_ + o0;
        float eo[8];
#pragma unroll
        for (int i = 0; i < 8; ++i) eo[i] = rfl(e_ope[i]);

        unsigned wAw = (ch == 0) ? mA.x : (ch == 1) ? mA.y : (ch == 2) ? mA.z : mA.w;
        unsigned wBw = (ch == 0) ? mB.x : (ch == 1) ? mB.y : (ch == 2) ? mB.z : mB.w;
        unsigned amA = (wAw >> (y*8)) & 0xffu;
        unsigned amB = (wBw >> (y*8)) & 0xffu;

        float wiv[8], wov[8];

#define STAGE(IT) do { \
        float* _d = ST + (((IT) >> 1) & 1)*1024 + ((IT) & 1)*512; \
        gl_lds16(pi + (IT)*512, _d); \
        gl_lds16(po + (IT)*512, _d + 256); \
    } while(0)

#define COMP(IT) do { \
        const float* _t = ST + (((IT) >> 1) & 1)*1024 + ((IT) & 1)*512; \
        float4 _i4 = *(const float4*)(_t + l*4); \
        float4 _u4 = *(const float4*)(_t + 256 + l*4); \
        float _einp = _i4.x*wiA + _i4.y*wiB + _i4.z*wiC + _i4.w*wiD; \
        float _eutp = _u4.x*woA + _u4.y*woB + _u4.z*woC + _u4.w*woD; \
        float _ein = _einp + __shfl_xor(_einp, 1); \
        float _eut = _eutp + __shfl_xor(_eutp, 1); \
        float _bs = eo[IT] + e_node_m; \
        float _si = _bs + _ein;  _si = _si > 0.f ? _si : SLOPE*_si; \
        float _so = _bs + _eut;  _so = _so > 0.f ? _so : SLOPE*_so; \
        float _wgi = ((amA >> (IT)) & 1u) ? __expf(_si) : 0.f; \
        float _wgo = ((amB >> (IT)) & 1u) ? __expf(_so) : 0.f; \
        wiv[IT] = _wgi; wov[IT] = _wgo; \
        ai0 += _wgi*_i4.x; ai1 += _wgi*_i4.y; ai2 += _wgi*_i4.z; ai3 += _wgi*_i4.w; \
        s0  += _u4.x;      s1  += _u4.y;      s2  += _u4.z;      s3  += _u4.w; \
        lsum += p ? _wgo : _wgi; \
    } while(0)

        STAGE(0); STAGE(1); STAGE(2); STAGE(3);   // 8 loads outstanding
        WAITV(6); COMP(0);
        WAITV(4); COMP(1);
        WAITL();  STAGE(4); STAGE(5);             // rebuffer buf0
        WAITV(6); COMP(2);
        WAITV(4); COMP(3);
        WAITL();  STAGE(6); STAGE(7);             // rebuffer buf1
        WAITV(6); COMP(4);
        WAITV(4); COMP(5);
        WAITV(2); COMP(6);
        WAITV(0); COMP(7);

#undef STAGE
#undef COMP

        // deferred feat_opes-weighted sums (L2-hot, off the staged critical path)
        const float* fo = feat_opes + (size_t)(b*O_ + o0)*INO + p*8;
#pragma unroll
        for (int it = 0; it < 8; ++it) {
            float4 f0 = *(const float4*)(fo + it*INO);
            float4 f1 = *(const float4*)(fo + it*INO + 4);
            float wgi = wiv[it], wgo = wov[it];
            aoi[0] += wgi*f0.x; aoi[1] += wgi*f0.y; aoi[2] += wgi*f0.z; aoi[3] += wgi*f0.w;
            aoi[4] += wgi*f1.x; aoi[5] += wgi*f1.y; aoi[6] += wgi*f1.z; aoi[7] += wgi*f1.w;
            aoo[0] += wgo*f0.x; aoo[1] += wgo*f0.y; aoo[2] += wgo*f0.z; aoo[3] += wgo*f0.w;
            aoo[4] += wgo*f1.x; aoo[5] += wgo*f1.y; aoo[6] += wgo*f1.z; aoo[7] += wgo*f1.w;
        }
    }

    // pack parity-split state vector (25 fields per lane)
    float v[25];
    v[0] = lsum;
    v[1] = ai0; v[2] = ai1; v[3] = ai2; v[4] = ai3;
#pragma unroll
    for (int j = 0; j < 8; ++j) { v[5+j] = aoi[j]; v[13+j] = aoo[j]; }
    v[21] = s0; v[22] = s1; v[23] = s2; v[24] = s3;

    // intra-block additive reduction reusing smem (staging fully consumed)
    __syncthreads();
    if (y > 0) {
#pragma unroll
        for (int q = 0; q < 25; ++q) smem[(y-1)*1600 + q*64 + l] = v[q];
    }
    __syncthreads();
    if (y == 0) {
#pragma unroll
        for (int q = 0; q < 25; ++q)
            v[q] += smem[q*64 + l] + smem[1600 + q*64 + l] + smem[3200 + q*64 + l];
        // plain coalesced partial stores: 25 x 256B contiguous runs
        float* pp = ws + WS_PART + (size_t)bid*NPQ;
#pragma unroll
        for (int q = 0; q < 25; ++q)
            pp[q*64 + l] = v[q];
    }
}

// ---------------- kernel B: fused 8-way reduce + epilogue ----------------
__global__ __launch_bounds__(256) void k_redfin(
        const float* __restrict__ W_ope,
        const float* __restrict__ W_arc_in,
        const float* __restrict__ W_arc_out,
        const float* __restrict__ ws,
        float* __restrict__ out) {
    int tid = threadIdx.x;
    int bid = blockIdx.x;           // [0,64)
    int h  = bid & 1;
    int b  = (bid >> 1) & (B_ - 1);
    int br = bid >> 5;

    __shared__ float sW[1024];      // [0..511]=W_ope, [512..767]=W_arc_in, [768..1023]=W_arc_out
    __shared__ float red2[25*64];   // reduced partials for this (br,b,h)
    __shared__ float cinv[32][3];   // per-column inv_i, inv_o, akk

    for (int i = tid; i < 512; i += 256) sW[i] = W_ope[i];
    if (tid < 256) { sW[512 + tid] = W_arc_in[tid]; sW[768 + tid] = W_arc_out[tid]; }

    // 8-way reduction over the group's cq8 blocks (dense 256B runs)
    const float* part = ws + WS_PART;
    int pbase = (br*32 + b*2 + h)*NCQ8;  // k_main bid of cq8=0
    for (int ot = tid; ot < 25*64; ot += 256) {
        float s = 0.f;
#pragma unroll
        for (int c2 = 0; c2 < NCQ8; ++c2)
            s += part[(size_t)(pbase + c2)*NPQ + ot];
        red2[ot] = s;
    }
    __syncthreads();

    // per-column scalars
    if (tid < 32) {
        int j = tid;
        int col = (br*B_ + b)*M_ + h*32 + j;
        float li = red2[2*j];            // field 0 @ even lane = l_in
        float lo = red2[2*j + 1];        // field 0 @ odd lane  = l_out
        float en  = ws[WS_ENODE + col];
        float ekk = 2.f*en; ekk = ekk > 0.f ? ekk : SLOPE*ekk;
        float wkk = __expf(ekk);
        float inv_i = 1.f/(li + wkk);
        float inv_o = 1.f/(lo + wkk);
        cinv[j][0] = inv_i;
        cinv[j][1] = inv_o;
        cinv[j][2] = wkk*inv_i + wkk*inv_o;
    }
    __syncthreads();

    // epilogue: 32 columns x 32 outputs; thread -> (j, 4 c's)
    int j  = tid >> 3;
    int c0 = tid & 7;
    int col = (br*B_ + b)*M_ + h*32 + j;
    int l0 = 2*j, l1 = 2*j + 1;

    float vai[8], vsao[8], vaoi[16], vaoo[16];
#pragma unroll
    for (int k = 0; k < 4; ++k) {
        vai[k]    = red2[(1+k)*64  + l0];
        vai[4+k]  = red2[(1+k)*64  + l1];
        vsao[k]   = red2[(21+k)*64 + l0];
        vsao[4+k] = red2[(21+k)*64 + l1];
    }
#pragma unroll
    for (int k = 0; k < 8; ++k) {
        vaoi[k]   = red2[(5+k)*64  + l0];
        vaoi[8+k] = red2[(5+k)*64  + l1];
        vaoo[k]   = red2[(13+k)*64 + l0];
        vaoo[8+k] = red2[(13+k)*64 + l1];
    }

    float inv_i = cinv[j][0], inv_o = cinv[j][1], akk = cinv[j][2];
    const float* pn = ws + WS_PNODE + (size_t)col*C_;
    float* op = out + (size_t)col*C_;

#pragma unroll
    for (int k = 0; k < 4; ++k) {
        int c = c0 + 8*k;
        float s_ai = 0.f, s_oi = 0.f, s_ao = 0.f, s_oo = 0.f;
#pragma unroll
        for (int q = 0; q < 8; ++q) {
            s_ai += vai[q] *sW[512 + q*C_ + c];
            s_ao += vsao[q]*sW[768 + q*C_ + c];
        }
#pragma unroll
        for (int q = 0; q < 16; ++q) {
            float wv = sW[q*C_ + c];
            s_oi += vaoi[q]*wv;
            s_oo += vaoo[q]*wv;
        }
        float x = (s_ai + s_oi)*inv_i + s_ao + s_oo*inv_o + pn[c]*akk;
        op[c] = 1.f/(1.f + __expf(-x));
    }
}

extern "C" void kernel_launch(void* const* d_in, const int* in_sizes, int n_in,
                              void* d_out, int out_size, void* d_ws, size_t ws_size,
                              hipStream_t stream) {
    const float* adj0 = (const float*)d_in[0];
    const float* adj1 = (const float*)d_in[1];
    const float* adj2 = (const float*)d_in[2];
    const float* adj3 = (const float*)d_in[3];
    // d_in[4] = batch_idxes (unused by the reference)
    const float* feat_opes       = (const float*)d_in[5];
    const float* feat_mas        = (const float*)d_in[6];
    const float* feat_buf        = (const float*)d_in[7];
    const float* feat_arc_ma_in  = (const float*)d_in[8];
    const float* feat_arc_buf_in = (const float*)d_in[9];
    const float* feat_arc_ma_out = (const float*)d_in[10];
    const float* feat_arc_buf_out= (const float*)d_in[11];
    const float* W_ope    = (const float*)d_in[12];
    const float* W_mas    = (const float*)d_in[13];
    const float* W_buf    = (const float*)d_in[14];
    const float* W_arc_in = (const float*)d_in[15];
    const float* W_arc_out= (const float*)d_in[16];
    const float* attn_ope = (const float*)d_in[17];
    const float* attn_mas = (const float*)d_in[18];
    const float* attn_arc = (const float*)d_in[19];

    float* ws  = (float*)d_ws;
    float* out = (float*)d_out;

    // ws need: 92176 + 512*1600 floats ~= 3.65 MB (prior rounds confirmed >=13.4 MB)
    if (ws_size < (size_t)(WS_PART + GRID*NPQ)*sizeof(float)) return;

    // 64 e_ope + 8 p_node + 1 w_arc + 16 mask-pack blocks
    k_pre<<<89, 256, 0, stream>>>(adj0, adj1, adj2, adj3,
                                  feat_opes, feat_mas, feat_buf,
                                  W_ope, W_mas, W_buf, W_arc_in, W_arc_out,
                                  attn_ope, attn_mas, attn_arc, ws);

    k_main<<<GRID, 256, 0, stream>>>(feat_opes,
                                     feat_arc_ma_in, feat_arc_buf_in,
                                     feat_arc_ma_out, feat_arc_buf_out, ws);

    k_redfin<<<2*B_*2, 256, 0, stream>>>(W_ope, W_arc_in, W_arc_out, ws, out);
}

// Round 6
// 208.870 us; speedup vs baseline: 1.9553x; 1.0197x over previous
//
#include <hip/hip_runtime.h>
#include <math.h>

#define B_   16
#define O_   1024
#define M_   64
#define C_   32
#define INO  16
#define INA  8
#define SLOPE 0.2f

// per-block partials: 25 parity-split fields x 64 lanes
#define NPQ   1600
#define NCH   4              // sequential o-chunks (of 32) per block
#define NCQ8  8              // o super-groups: 8 x 128 rows
#define GRID  (2*B_*2*NCQ8)  // 512 blocks

// workspace layout (float offsets)
#define WS_EOPE   0
#define WS_ENODE  (WS_EOPE + B_*O_)              // 16384
#define WS_PNODE  (WS_ENODE + 2*B_*M_)           // 18432
#define WS_WARC   (WS_PNODE + 2*B_*M_*C_)        // 83968
#define WS_MASK   (WS_WARC + 16)                 // 83984 (8192 floats = 32 KB packed adj bits)
#define WS_PART   (WS_MASK + 8192)               // 92176 (GRID*NPQ floats = 3.3 MB)

typedef float f32x4 __attribute__((ext_vector_type(4)));

__device__ inline float rfl(float x) {
    return __int_as_float(__builtin_amdgcn_readfirstlane(__float_as_int(x)));
}

// non-temporal (no-allocate) 16B load: the arc streams have ZERO reuse, so
// keep them out of L1/L2/MALL. This is the first clean test of the cache-
// service-path theory: r0-r5 all read through the mixed L3-hit/HBM path at
// an invariant ~2.7 TB/s; FETCH_SIZE must jump ~67->~134 MB if NT works.
__device__ __forceinline__ f32x4 ntload4(const float* p) {
    return __builtin_nontemporal_load((const f32x4*)p);
}

// ---------------- kernel 0: precompute (e_ope, p_node/e_node, w_arc, adj bitmasks) ----------------
__global__ void k_pre(const float* __restrict__ adj0, const float* __restrict__ adj1,
                      const float* __restrict__ adj2, const float* __restrict__ adj3,
                      const float* __restrict__ feat_opes,
                      const float* __restrict__ feat_mas,
                      const float* __restrict__ feat_buf,
                      const float* __restrict__ W_ope,
                      const float* __restrict__ W_mas,
                      const float* __restrict__ W_buf,
                      const float* __restrict__ W_arc_in,
                      const float* __restrict__ W_arc_out,
                      const float* __restrict__ attn_ope,
                      const float* __restrict__ attn_mas,
                      const float* __restrict__ attn_arc,
                      float* __restrict__ ws) {
    int tid = threadIdx.x;
    int bid = blockIdx.x;
    if (bid < 64) {
        // e_ope[b,o] = feat_opes[b,o,:] . (W_ope @ attn_ope)
        __shared__ float wo[INO];
        if (tid < INO) {
            float s = 0.f;
            for (int c = 0; c < C_; ++c) s += W_ope[tid*C_ + c]*attn_ope[c];
            wo[tid] = s;
        }
        __syncthreads();
        int idx = bid*256 + tid;                 // [0, 16384)
        const float* f = feat_opes + idx*INO;
        float s = 0.f;
#pragma unroll
        for (int j = 0; j < INO; ++j) s += f[j]*wo[j];
        ws[WS_EOPE + idx] = s;
    } else if (bid < 72) {
        // p_node / e_node for both branches
        int idx = (bid - 64)*256 + tid;          // [0, 2048)
        int br  = idx >> 10;
        int rem = idx & 1023;
        const float* f = (br == 0 ? feat_mas : feat_buf) + rem*INA;
        const float* W = (br == 0 ? W_mas : W_buf);
        float f8[INA];
#pragma unroll
        for (int k = 0; k < INA; ++k) f8[k] = f[k];
        float e = 0.f;
        float* pn = ws + WS_PNODE + idx*C_;
        for (int c = 0; c < C_; ++c) {
            float s = 0.f;
#pragma unroll
            for (int k = 0; k < INA; ++k) s += f8[k]*W[k*C_ + c];
            pn[c] = s;
            e += s*attn_mas[c];
        }
        ws[WS_ENODE + idx] = e;
    } else if (bid == 72) {
        // w_arc_in/out 8-vectors: W_arc @ attn_arc
        if (tid < 16) {
            const float* W = (tid < 8) ? W_arc_in : W_arc_out;
            int k = tid & 7;
            float s = 0.f;
            for (int c = 0; c < C_; ++c) s += W[k*C_ + c]*attn_arc[c];
            ws[WS_WARC + tid] = s;
        }
    } else {
        // packed adjacency bitmasks: per (br,m) 64 uints = A bits[32] | B bits[32]
        int idx = (bid - 73)*256 + tid;          // [0, 4096)
        int br  = idx >> 11;
        int rem = idx & 2047;
        int mm  = rem >> 5;
        int j4  = rem & 31;
        const float* Ai = br ? adj2 : adj0;
        const float* Ao = br ? adj3 : adj1;
        unsigned a = 0u, bm = 0u;
        for (int t = 0; t < 32; ++t) {
            int o = j4*32 + t;
            a  |= (Ai[o*M_ + mm] == 1.0f) ? (1u << t) : 0u;
            bm |= (Ao[o*M_ + mm] == 1.0f) ? (1u << t) : 0u;
        }
        unsigned* mp = (unsigned*)(ws + WS_MASK) + (br*M_ + mm)*64;
        mp[j4]      = a;
        mp[32 + j4] = bm;
    }
}

// ---------------- kernel A: main streaming pass (NT arc loads) ----------------
// r5 structure verbatim (512 blocks x 4 sequential chunks, packed masks,
// parity-split lanes, plain partial stores). ONE change: the arc streams are
// read with __builtin_nontemporal_load into a 4-deep rotating register
// buffer instead of cached global_load_lds. Register-vs-LDS staging was
// proven perf-equivalent (r1 vs r3, both ~50us), so the only live variable
// is the cache policy on the stream.
__global__ __launch_bounds__(256) void k_main(
        const float* __restrict__ feat_opes,
        const float* __restrict__ fin_ma,  const float* __restrict__ fin_buf,
        const float* __restrict__ fout_ma, const float* __restrict__ fout_buf,
        float* __restrict__ ws) {
    int tid = threadIdx.x;
    int l   = tid & 63;
    int p   = l & 1;                                  // k-half / field parity
    int y   = __builtin_amdgcn_readfirstlane(tid >> 6);

    int bid = blockIdx.x;                 // [0, 512)
    int cq8 = bid & (NCQ8 - 1);           // 128-row super-group
    int h   = (bid >> 3) & 1;             // m-half
    int b   = (bid >> 4) & (B_ - 1);
    int br  = bid >> 8;

    int m   = h*32 + (l >> 1);

    const float* fin   = br ? fin_buf  : fin_ma;
    const float* fout  = br ? fout_buf : fout_ma;

    // reduction-only LDS now (19.2 KB): 3 waves x 25 fields x 64 lanes
    __shared__ float smem[4800];

    float e_node_m = ws[WS_ENODE + (br*B_ + b)*M_ + m];

    // per-parity 4-element weight slices
    const float* wv = ws + WS_WARC + 4*p;
    float wiA = wv[0], wiB = wv[1], wiC = wv[2], wiD = wv[3];
    float woA = wv[8], woB = wv[9], woC = wv[10], woD = wv[11];

    // packed adjacency for this block's 128-row span: one uint4 per matrix
    const uint4* mp4 = (const uint4*)((const unsigned*)(ws + WS_MASK) + (br*M_ + m)*64);
    uint4 mA = mp4[cq8];
    uint4 mB = mp4[8 + cq8];

    const float* pib = fin  + (size_t)b*O_*512 + h*256 + l*4;
    const float* pob = fout + (size_t)b*O_*512 + h*256 + l*4;

    float ai0 = 0.f, ai1 = 0.f, ai2 = 0.f, ai3 = 0.f;
    float s0 = 0.f, s1 = 0.f, s2 = 0.f, s3 = 0.f;
    float lsum = 0.f;
    float aoi[8], aoo[8];
#pragma unroll
    for (int j = 0; j < 8; ++j) { aoi[j] = 0.f; aoo[j] = 0.f; }

#pragma unroll
    for (int ch = 0; ch < NCH; ++ch) {
        int o0 = cq8*128 + ch*32 + y*8;   // this wave: o in [o0, o0+8)
        const float* pi = pib + (size_t)o0*512;
        const float* po = pob + (size_t)o0*512;

        // wave-uniform e_ope -> SGPRs
        const float* e_ope = ws + WS_EOPE + b*O_ + o0;
        float eo[8];
#pragma unroll
        for (int i = 0; i < 8; ++i) eo[i] = rfl(e_ope[i]);

        unsigned wAw = (ch == 0) ? mA.x : (ch == 1) ? mA.y : (ch == 2) ? mA.z : mA.w;
        unsigned wBw = (ch == 0) ? mB.x : (ch == 1) ? mB.y : (ch == 2) ? mB.z : mB.w;
        unsigned amA = (wAw >> (y*8)) & 0xffu;
        unsigned amB = (wBw >> (y*8)) & 0xffu;

        float wiv[8], wov[8];

        // 4-deep rotating NT register pipeline
        f32x4 bi[4], bu[4];
#pragma unroll
        for (int q = 0; q < 4; ++q) {
            bi[q] = ntload4(pi + q*512);
            bu[q] = ntload4(po + q*512);
        }

#pragma unroll
        for (int it = 0; it < 8; ++it) {
            const int sl = it & 3;
            f32x4 i4 = bi[sl], u4 = bu[sl];
            if (it + 4 < 8) {
                bi[sl] = ntload4(pi + (it+4)*512);
                bu[sl] = ntload4(po + (it+4)*512);
            }
            float einp = i4.x*wiA + i4.y*wiB + i4.z*wiC + i4.w*wiD;
            float eutp = u4.x*woA + u4.y*woB + u4.z*woC + u4.w*woD;
            float ein = einp + __shfl_xor(einp, 1);
            float eut = eutp + __shfl_xor(eutp, 1);
            float bs = eo[it] + e_node_m;
            float si = bs + ein;  si = si > 0.f ? si : SLOPE*si;
            float so = bs + eut;  so = so > 0.f ? so : SLOPE*so;
            float wgi = ((amA >> it) & 1u) ? __expf(si) : 0.f;
            float wgo = ((amB >> it) & 1u) ? __expf(so) : 0.f;
            wiv[it] = wgi; wov[it] = wgo;
            ai0 += wgi*i4.x; ai1 += wgi*i4.y; ai2 += wgi*i4.z; ai3 += wgi*i4.w;
            s0  += u4.x;     s1  += u4.y;     s2  += u4.z;     s3  += u4.w;
            lsum += p ? wgo : wgi;
        }

        // deferred feat_opes-weighted sums (reused rows -> normal cached loads)
        const float* fo = feat_opes + (size_t)(b*O_ + o0)*INO + p*8;
#pragma unroll
        for (int it = 0; it < 8; ++it) {
            float4 f0 = *(const float4*)(fo + it*INO);
            float4 f1 = *(const float4*)(fo + it*INO + 4);
            float wgi = wiv[it], wgo = wov[it];
            aoi[0] += wgi*f0.x; aoi[1] += wgi*f0.y; aoi[2] += wgi*f0.z; aoi[3] += wgi*f0.w;
            aoi[4] += wgi*f1.x; aoi[5] += wgi*f1.y; aoi[6] += wgi*f1.z; aoi[7] += wgi*f1.w;
            aoo[0] += wgo*f0.x; aoo[1] += wgo*f0.y; aoo[2] += wgo*f0.z; aoo[3] += wgo*f0.w;
            aoo[4] += wgo*f1.x; aoo[5] += wgo*f1.y; aoo[6] += wgo*f1.z; aoo[7] += wgo*f1.w;
        }
    }

    // pack parity-split state vector (25 fields per lane)
    float v[25];
    v[0] = lsum;
    v[1] = ai0; v[2] = ai1; v[3] = ai2; v[4] = ai3;
#pragma unroll
    for (int j = 0; j < 8; ++j) { v[5+j] = aoi[j]; v[13+j] = aoo[j]; }
    v[21] = s0; v[22] = s1; v[23] = s2; v[24] = s3;

    // intra-block additive reduction (waves 1..3 -> wave 0)
    __syncthreads();
    if (y > 0) {
#pragma unroll
        for (int q = 0; q < 25; ++q) smem[(y-1)*1600 + q*64 + l] = v[q];
    }
    __syncthreads();
    if (y == 0) {
#pragma unroll
        for (int q = 0; q < 25; ++q)
            v[q] += smem[q*64 + l] + smem[1600 + q*64 + l] + smem[3200 + q*64 + l];
        // plain coalesced partial stores: 25 x 256B contiguous runs
        float* pp = ws + WS_PART + (size_t)bid*NPQ;
#pragma unroll
        for (int q = 0; q < 25; ++q)
            pp[q*64 + l] = v[q];
    }
}

// ---------------- kernel B: fused 8-way reduce + epilogue ----------------
__global__ __launch_bounds__(256) void k_redfin(
        const float* __restrict__ W_ope,
        const float* __restrict__ W_arc_in,
        const float* __restrict__ W_arc_out,
        const float* __restrict__ ws,
        float* __restrict__ out) {
    int tid = threadIdx.x;
    int bid = blockIdx.x;           // [0,64)
    int h  = bid & 1;
    int b  = (bid >> 1) & (B_ - 1);
    int br = bid >> 5;

    __shared__ float sW[1024];      // [0..511]=W_ope, [512..767]=W_arc_in, [768..1023]=W_arc_out
    __shared__ float red2[25*64];   // reduced partials for this (br,b,h)
    __shared__ float cinv[32][3];   // per-column inv_i, inv_o, akk

    for (int i = tid; i < 512; i += 256) sW[i] = W_ope[i];
    if (tid < 256) { sW[512 + tid] = W_arc_in[tid]; sW[768 + tid] = W_arc_out[tid]; }

    // 8-way reduction over the group's cq8 blocks (dense 256B runs)
    const float* part = ws + WS_PART;
    int pbase = (br*32 + b*2 + h)*NCQ8;  // k_main bid of cq8=0
    for (int ot = tid; ot < 25*64; ot += 256) {
        float s = 0.f;
#pragma unroll
        for (int c2 = 0; c2 < NCQ8; ++c2)
            s += part[(size_t)(pbase + c2)*NPQ + ot];
        red2[ot] = s;
    }
    __syncthreads();

    // per-column scalars
    if (tid < 32) {
        int j = tid;
        int col = (br*B_ + b)*M_ + h*32 + j;
        float li = red2[2*j];            // field 0 @ even lane = l_in
        float lo = red2[2*j + 1];        // field 0 @ odd lane  = l_out
        float en  = ws[WS_ENODE + col];
        float ekk = 2.f*en; ekk = ekk > 0.f ? ekk : SLOPE*ekk;
        float wkk = __expf(ekk);
        float inv_i = 1.f/(li + wkk);
        float inv_o = 1.f/(lo + wkk);
        cinv[j][0] = inv_i;
        cinv[j][1] = inv_o;
        cinv[j][2] = wkk*inv_i + wkk*inv_o;
    }
    __syncthreads();

    // epilogue: 32 columns x 32 outputs; thread -> (j, 4 c's)
    int j  = tid >> 3;
    int c0 = tid & 7;
    int col = (br*B_ + b)*M_ + h*32 + j;
    int l0 = 2*j, l1 = 2*j + 1;

    float vai[8], vsao[8], vaoi[16], vaoo[16];
#pragma unroll
    for (int k = 0; k < 4; ++k) {
        vai[k]    = red2[(1+k)*64  + l0];
        vai[4+k]  = red2[(1+k)*64  + l1];
        vsao[k]   = red2[(21+k)*64 + l0];
        vsao[4+k] = red2[(21+k)*64 + l1];
    }
#pragma unroll
    for (int k = 0; k < 8; ++k) {
        vaoi[k]   = red2[(5+k)*64  + l0];
        vaoi[8+k] = red2[(5+k)*64  + l1];
        vaoo[k]   = red2[(13+k)*64 + l0];
        vaoo[8+k] = red2[(13+k)*64 + l1];
    }

    float inv_i = cinv[j][0], inv_o = cinv[j][1], akk = cinv[j][2];
    const float* pn = ws + WS_PNODE + (size_t)col*C_;
    float* op = out + (size_t)col*C_;

#pragma unroll
    for (int k = 0; k < 4; ++k) {
        int c = c0 + 8*k;
        float s_ai = 0.f, s_oi = 0.f, s_ao = 0.f, s_oo = 0.f;
#pragma unroll
        for (int q = 0; q < 8; ++q) {
            s_ai += vai[q] *sW[512 + q*C_ + c];
            s_ao += vsao[q]*sW[768 + q*C_ + c];
        }
#pragma unroll
        for (int q = 0; q < 16; ++q) {
            float wv = sW[q*C_ + c];
            s_oi += vaoi[q]*wv;
            s_oo += vaoo[q]*wv;
        }
        float x = (s_ai + s_oi)*inv_i + s_ao + s_oo*inv_o + pn[c]*akk;
        op[c] = 1.f/(1.f + __expf(-x));
    }
}

extern "C" void kernel_launch(void* const* d_in, const int* in_sizes, int n_in,
                              void* d_out, int out_size, void* d_ws, size_t ws_size,
                              hipStream_t stream) {
    const float* adj0 = (const float*)d_in[0];
    const float* adj1 = (const float*)d_in[1];
    const float* adj2 = (const float*)d_in[2];
    const float* adj3 = (const float*)d_in[3];
    // d_in[4] = batch_idxes (unused by the reference)
    const float* feat_opes       = (const float*)d_in[5];
    const float* feat_mas        = (const float*)d_in[6];
    const float* feat_buf        = (const float*)d_in[7];
    const float* feat_arc_ma_in  = (const float*)d_in[8];
    const float* feat_arc_buf_in = (const float*)d_in[9];
    const float* feat_arc_ma_out = (const float*)d_in[10];
    const float* feat_arc_buf_out= (const float*)d_in[11];
    const float* W_ope    = (const float*)d_in[12];
    const float* W_mas    = (const float*)d_in[13];
    const float* W_buf    = (const float*)d_in[14];
    const float* W_arc_in = (const float*)d_in[15];
    const float* W_arc_out= (const float*)d_in[16];
    const float* attn_ope = (const float*)d_in[17];
    const float* attn_mas = (const float*)d_in[18];
    const float* attn_arc = (const float*)d_in[19];

    float* ws  = (float*)d_ws;
    float* out = (float*)d_out;

    if (ws_size < (size_t)(WS_PART + GRID*NPQ)*sizeof(float)) return;

    // 64 e_ope + 8 p_node + 1 w_arc + 16 mask-pack blocks
    k_pre<<<89, 256, 0, stream>>>(adj0, adj1, adj2, adj3,
                                  feat_opes, feat_mas, feat_buf,
                                  W_ope, W_mas, W_buf, W_arc_in, W_arc_out,
                                  attn_ope, attn_mas, attn_arc, ws);

    k_main<<<GRID, 256, 0, stream>>>(feat_opes,
                                     feat_arc_ma_in, feat_arc_buf_in,
                                     feat_arc_ma_out, feat_arc_buf_out, ws);

    k_redfin<<<2*B_*2, 256, 0, stream>>>(W_ope, W_arc_in, W_arc_out, ws, out);
}

// Round 7
// 206.571 us; speedup vs baseline: 1.9771x; 1.0111x over previous
//
#include <hip/hip_runtime.h>
#include <math.h>

#define B_   16
#define O_   1024
#define M_   64
#define C_   32
#define INO  16
#define INA  8
#define SLOPE 0.2f

// per-block partials: 25 parity-split fields x 64 lanes
#define NPQ   1600
#define NCH   2              // sequential o-chunks (of 32) per block
#define NSG   16             // o super-groups: 16 x 64 rows
#define GRID  (2*B_*2*NSG)   // 1024 blocks = 4/CU = 16 waves/CU (VGPR-128 cap)

// workspace layout (float offsets)
#define WS_EOPE   0
#define WS_ENODE  (WS_EOPE + B_*O_)              // 16384
#define WS_PNODE  (WS_ENODE + 2*B_*M_)           // 18432
#define WS_WARC   (WS_PNODE + 2*B_*M_*C_)        // 83968
#define WS_MASK   (WS_WARC + 16)                 // 83984 (8192 floats = 32 KB packed adj bits)
#define WS_PART   (WS_MASK + 8192)               // 92176 (GRID*NPQ floats = 6.5 MB)

typedef float f32x4 __attribute__((ext_vector_type(4)));

__device__ inline float rfl(float x) {
    return __int_as_float(__builtin_amdgcn_readfirstlane(__float_as_int(x)));
}

// non-temporal (no-allocate) 16B load. r6 result: this was the first lever in
// 7 rounds that moved k_main (52 -> <39.5us) -- the mixed L3/HBM service path
// was the 2.7 TB/s cap, and NT bypasses it.
__device__ __forceinline__ f32x4 ntload4(const float* p) {
    return __builtin_nontemporal_load((const f32x4*)p);
}
__device__ __forceinline__ void ntstore(float* p, float v) {
    __builtin_nontemporal_store(v, p);
}

// ---------------- kernel 0: precompute (e_ope, p_node/e_node, w_arc, adj bitmasks) ----------------
__global__ void k_pre(const float* __restrict__ adj0, const float* __restrict__ adj1,
                      const float* __restrict__ adj2, const float* __restrict__ adj3,
                      const float* __restrict__ feat_opes,
                      const float* __restrict__ feat_mas,
                      const float* __restrict__ feat_buf,
                      const float* __restrict__ W_ope,
                      const float* __restrict__ W_mas,
                      const float* __restrict__ W_buf,
                      const float* __restrict__ W_arc_in,
                      const float* __restrict__ W_arc_out,
                      const float* __restrict__ attn_ope,
                      const float* __restrict__ attn_mas,
                      const float* __restrict__ attn_arc,
                      float* __restrict__ ws) {
    int tid = threadIdx.x;
    int bid = blockIdx.x;
    if (bid < 64) {
        // e_ope[b,o] = feat_opes[b,o,:] . (W_ope @ attn_ope)
        __shared__ float wo[INO];
        if (tid < INO) {
            float s = 0.f;
            for (int c = 0; c < C_; ++c) s += W_ope[tid*C_ + c]*attn_ope[c];
            wo[tid] = s;
        }
        __syncthreads();
        int idx = bid*256 + tid;                 // [0, 16384)
        const float* f = feat_opes + idx*INO;
        float s = 0.f;
#pragma unroll
        for (int j = 0; j < INO; ++j) s += f[j]*wo[j];
        ws[WS_EOPE + idx] = s;
    } else if (bid < 72) {
        // p_node / e_node for both branches
        int idx = (bid - 64)*256 + tid;          // [0, 2048)
        int br  = idx >> 10;
        int rem = idx & 1023;
        const float* f = (br == 0 ? feat_mas : feat_buf) + rem*INA;
        const float* W = (br == 0 ? W_mas : W_buf);
        float f8[INA];
#pragma unroll
        for (int k = 0; k < INA; ++k) f8[k] = f[k];
        float e = 0.f;
        float* pn = ws + WS_PNODE + idx*C_;
        for (int c = 0; c < C_; ++c) {
            float s = 0.f;
#pragma unroll
            for (int k = 0; k < INA; ++k) s += f8[k]*W[k*C_ + c];
            pn[c] = s;
            e += s*attn_mas[c];
        }
        ws[WS_ENODE + idx] = e;
    } else if (bid == 72) {
        // w_arc_in/out 8-vectors: W_arc @ attn_arc
        if (tid < 16) {
            const float* W = (tid < 8) ? W_arc_in : W_arc_out;
            int k = tid & 7;
            float s = 0.f;
            for (int c = 0; c < C_; ++c) s += W[k*C_ + c]*attn_arc[c];
            ws[WS_WARC + tid] = s;
        }
    } else {
        // packed adjacency bitmasks: per (br,m) 64 uints = A bits[32] | B bits[32]
        int idx = (bid - 73)*256 + tid;          // [0, 4096)
        int br  = idx >> 11;
        int rem = idx & 2047;
        int mm  = rem >> 5;
        int j4  = rem & 31;
        const float* Ai = br ? adj2 : adj0;
        const float* Ao = br ? adj3 : adj1;
        unsigned a = 0u, bm = 0u;
        for (int t = 0; t < 32; ++t) {
            int o = j4*32 + t;
            a  |= (Ai[o*M_ + mm] == 1.0f) ? (1u << t) : 0u;
            bm |= (Ao[o*M_ + mm] == 1.0f) ? (1u << t) : 0u;
        }
        unsigned* mp = (unsigned*)(ws + WS_MASK) + (br*M_ + mm)*64;
        mp[j4]      = a;
        mp[32 + j4] = bm;
    }
}

// ---------------- kernel A: main streaming pass (NT + continuous pipeline) ----------------
// r6 body with two latency-hiding fixes (NT made every arc load a full
// ~900-cyc HBM access; MLP is now the binding constraint):
//  1. grid 512->1024 (NCH 4->2): 4 blocks/CU -> 16 waves/CU (VGPR-128 cap).
//  2. cross-chunk prefetch: the 4-deep NT rotation is hoisted out of the
//     chunk loop; during a chunk's back half we prefetch the NEXT chunk's
//     first 4 rows, so the NT stream never drains across the feat pass.
__global__ __launch_bounds__(256) void k_main(
        const float* __restrict__ feat_opes,
        const float* __restrict__ fin_ma,  const float* __restrict__ fin_buf,
        const float* __restrict__ fout_ma, const float* __restrict__ fout_buf,
        float* __restrict__ ws) {
    int tid = threadIdx.x;
    int l   = tid & 63;
    int p   = l & 1;                                  // k-half / field parity
    int y   = __builtin_amdgcn_readfirstlane(tid >> 6);

    int bid = blockIdx.x;                 // [0, 1024)
    int sg  = bid & (NSG - 1);            // 64-row super-group
    int h   = (bid >> 4) & 1;             // m-half
    int b   = (bid >> 5) & (B_ - 1);
    int br  = bid >> 9;

    int m   = h*32 + (l >> 1);

    const float* fin   = br ? fin_buf  : fin_ma;
    const float* fout  = br ? fout_buf : fout_ma;

    // reduction-only LDS (19.2 KB): 3 waves x 25 fields x 64 lanes
    __shared__ float smem[4800];

    float e_node_m = ws[WS_ENODE + (br*B_ + b)*M_ + m];

    // per-parity 4-element weight slices
    const float* wv = ws + WS_WARC + 4*p;
    float wiA = wv[0], wiB = wv[1], wiC = wv[2], wiD = wv[3];
    float woA = wv[8], woB = wv[9], woC = wv[10], woD = wv[11];

    // packed adjacency for this block's 64-row span: one uint2 per matrix
    const uint2* mp2 = (const uint2*)((const unsigned*)(ws + WS_MASK) + (br*M_ + m)*64);
    uint2 mA = mp2[sg];
    uint2 mB = mp2[16 + sg];

    const float* pib = fin  + (size_t)b*O_*512 + h*256 + l*4;
    const float* pob = fout + (size_t)b*O_*512 + h*256 + l*4;

    int o0b = sg*64 + y*8;                // this wave's chunk-0 row base
    const float* pi = pib + (size_t)o0b*512;
    const float* po = pob + (size_t)o0b*512;

    float ai0 = 0.f, ai1 = 0.f, ai2 = 0.f, ai3 = 0.f;
    float s0 = 0.f, s1 = 0.f, s2 = 0.f, s3 = 0.f;
    float lsum = 0.f;
    float aoi[8], aoo[8];
#pragma unroll
    for (int j = 0; j < 8; ++j) { aoi[j] = 0.f; aoo[j] = 0.f; }

    // hoisted 4-deep rotating NT pipeline (lives across chunks)
    f32x4 bi[4], bu[4];
#pragma unroll
    for (int q = 0; q < 4; ++q) {
        bi[q] = ntload4(pi + q*512);
        bu[q] = ntload4(po + q*512);
    }

#pragma unroll
    for (int ch = 0; ch < NCH; ++ch) {
        int o0 = o0b + ch*32;
        const float* pc = pi + (size_t)ch*32*512;   // current chunk row-0 addr
        const float* uc = po + (size_t)ch*32*512;

        // wave-uniform e_ope -> SGPRs (64 KB table, L2-hot)
        const float* e_ope = ws + WS_EOPE + b*O_ + o0;
        float eo[8];
#pragma unroll
        for (int i = 0; i < 8; ++i) eo[i] = rfl(e_ope[i]);

        unsigned wAw = ch ? mA.y : mA.x;
        unsigned wBw = ch ? mB.y : mB.x;
        unsigned amA = (wAw >> (y*8)) & 0xffu;
        unsigned amB = (wBw >> (y*8)) & 0xffu;

        float wiv[8], wov[8];

#pragma unroll
        for (int it = 0; it < 8; ++it) {
            const int sl = it & 3;
            f32x4 i4 = bi[sl], u4 = bu[sl];
            if (it < 4) {
                // back half of this chunk
                bi[sl] = ntload4(pc + (it+4)*512);
                bu[sl] = ntload4(uc + (it+4)*512);
            } else if (ch + 1 < NCH) {
                // front half of the NEXT chunk (rows +32..+35)
                bi[sl] = ntload4(pc + (32 + it - 4)*512);
                bu[sl] = ntload4(uc + (32 + it - 4)*512);
            }
            float einp = i4.x*wiA + i4.y*wiB + i4.z*wiC + i4.w*wiD;
            float eutp = u4.x*woA + u4.y*woB + u4.z*woC + u4.w*woD;
            float ein = einp + __shfl_xor(einp, 1);
            float eut = eutp + __shfl_xor(eutp, 1);
            float bs = eo[it] + e_node_m;
            float si = bs + ein;  si = si > 0.f ? si : SLOPE*si;
            float so = bs + eut;  so = so > 0.f ? so : SLOPE*so;
            float wgi = ((amA >> it) & 1u) ? __expf(si) : 0.f;
            float wgo = ((amB >> it) & 1u) ? __expf(so) : 0.f;
            wiv[it] = wgi; wov[it] = wgo;
            ai0 += wgi*i4.x; ai1 += wgi*i4.y; ai2 += wgi*i4.z; ai3 += wgi*i4.w;
            s0  += u4.x;     s1  += u4.y;     s2  += u4.z;     s3  += u4.w;
            lsum += p ? wgo : wgi;
        }

        // deferred feat_opes-weighted sums (reused rows -> cached loads);
        // runs while the next chunk's NT loads are in flight
        const float* fo = feat_opes + (size_t)(b*O_ + o0)*INO + p*8;
#pragma unroll
        for (int it = 0; it < 8; ++it) {
            float4 f0 = *(const float4*)(fo + it*INO);
            float4 f1 = *(const float4*)(fo + it*INO + 4);
            float wgi = wiv[it], wgo = wov[it];
            aoi[0] += wgi*f0.x; aoi[1] += wgi*f0.y; aoi[2] += wgi*f0.z; aoi[3] += wgi*f0.w;
            aoi[4] += wgi*f1.x; aoi[5] += wgi*f1.y; aoi[6] += wgi*f1.z; aoi[7] += wgi*f1.w;
            aoo[0] += wgo*f0.x; aoo[1] += wgo*f0.y; aoo[2] += wgo*f0.z; aoo[3] += wgo*f0.w;
            aoo[4] += wgo*f1.x; aoo[5] += wgo*f1.y; aoo[6] += wgo*f1.z; aoo[7] += wgo*f1.w;
        }
    }

    // pack parity-split state vector (25 fields per lane)
    float v[25];
    v[0] = lsum;
    v[1] = ai0; v[2] = ai1; v[3] = ai2; v[4] = ai3;
#pragma unroll
    for (int j = 0; j < 8; ++j) { v[5+j] = aoi[j]; v[13+j] = aoo[j]; }
    v[21] = s0; v[22] = s1; v[23] = s2; v[24] = s3;

    // intra-block additive reduction (waves 1..3 -> wave 0)
    __syncthreads();
    if (y > 0) {
#pragma unroll
        for (int q = 0; q < 25; ++q) smem[(y-1)*1600 + q*64 + l] = v[q];
    }
    __syncthreads();
    if (y == 0) {
#pragma unroll
        for (int q = 0; q < 25; ++q)
            v[q] += smem[q*64 + l] + smem[1600 + q*64 + l] + smem[3200 + q*64 + l];
        // write-once partials -> non-temporal coalesced stores
        float* pp = ws + WS_PART + (size_t)bid*NPQ;
#pragma unroll
        for (int q = 0; q < 25; ++q)
            ntstore(pp + q*64 + l, v[q]);
    }
}

// ---------------- kernel B: fused 16-way reduce + epilogue ----------------
__global__ __launch_bounds__(256) void k_redfin(
        const float* __restrict__ W_ope,
        const float* __restrict__ W_arc_in,
        const float* __restrict__ W_arc_out,
        const float* __restrict__ ws,
        float* __restrict__ out) {
    int tid = threadIdx.x;
    int bid = blockIdx.x;           // [0,64)
    int h  = bid & 1;
    int b  = (bid >> 1) & (B_ - 1);
    int br = bid >> 5;

    __shared__ float sW[1024];      // [0..511]=W_ope, [512..767]=W_arc_in, [768..1023]=W_arc_out
    __shared__ float red2[25*64];   // reduced partials for this (br,b,h)
    __shared__ float cinv[32][3];   // per-column inv_i, inv_o, akk

    for (int i = tid; i < 512; i += 256) sW[i] = W_ope[i];
    if (tid < 256) { sW[512 + tid] = W_arc_in[tid]; sW[768 + tid] = W_arc_out[tid]; }

    // 16-way reduction over the group's super-group blocks (dense 256B runs)
    const float* part = ws + WS_PART;
    int pbase = br*512 + b*32 + h*16;    // k_main bid of sg=0
    for (int ot = tid; ot < 25*64; ot += 256) {
        float s = 0.f;
#pragma unroll
        for (int c2 = 0; c2 < NSG; ++c2)
            s += part[(size_t)(pbase + c2)*NPQ + ot];
        red2[ot] = s;
    }
    __syncthreads();

    // per-column scalars
    if (tid < 32) {
        int j = tid;
        int col = (br*B_ + b)*M_ + h*32 + j;
        float li = red2[2*j];            // field 0 @ even lane = l_in
        float lo = red2[2*j + 1];        // field 0 @ odd lane  = l_out
        float en  = ws[WS_ENODE + col];
        float ekk = 2.f*en; ekk = ekk > 0.f ? ekk : SLOPE*ekk;
        float wkk = __expf(ekk);
        float inv_i = 1.f/(li + wkk);
        float inv_o = 1.f/(lo + wkk);
        cinv[j][0] = inv_i;
        cinv[j][1] = inv_o;
        cinv[j][2] = wkk*inv_i + wkk*inv_o;
    }
    __syncthreads();

    // epilogue: 32 columns x 32 outputs; thread -> (j, 4 c's)
    int j  = tid >> 3;
    int c0 = tid & 7;
    int col = (br*B_ + b)*M_ + h*32 + j;
    int l0 = 2*j, l1 = 2*j + 1;

    float vai[8], vsao[8], vaoi[16], vaoo[16];
#pragma unroll
    for (int k = 0; k < 4; ++k) {
        vai[k]    = red2[(1+k)*64  + l0];
        vai[4+k]  = red2[(1+k)*64  + l1];
        vsao[k]   = red2[(21+k)*64 + l0];
        vsao[4+k] = red2[(21+k)*64 + l1];
    }
#pragma unroll
    for (int k = 0; k < 8; ++k) {
        vaoi[k]   = red2[(5+k)*64  + l0];
        vaoi[8+k] = red2[(5+k)*64  + l1];
        vaoo[k]   = red2[(13+k)*64 + l0];
        vaoo[8+k] = red2[(13+k)*64 + l1];
    }

    float inv_i = cinv[j][0], inv_o = cinv[j][1], akk = cinv[j][2];
    const float* pn = ws + WS_PNODE + (size_t)col*C_;
    float* op = out + (size_t)col*C_;

#pragma unroll
    for (int k = 0; k < 4; ++k) {
        int c = c0 + 8*k;
        float s_ai = 0.f, s_oi = 0.f, s_ao = 0.f, s_oo = 0.f;
#pragma unroll
        for (int q = 0; q < 8; ++q) {
            s_ai += vai[q] *sW[512 + q*C_ + c];
            s_ao += vsao[q]*sW[768 + q*C_ + c];
        }
#pragma unroll
        for (int q = 0; q < 16; ++q) {
            float wv = sW[q*C_ + c];
            s_oi += vaoi[q]*wv;
            s_oo += vaoo[q]*wv;
        }
        float x = (s_ai + s_oi)*inv_i + s_ao + s_oo*inv_o + pn[c]*akk;
        op[c] = 1.f/(1.f + __expf(-x));
    }
}

extern "C" void kernel_launch(void* const* d_in, const int* in_sizes, int n_in,
                              void* d_out, int out_size, void* d_ws, size_t ws_size,
                              hipStream_t stream) {
    const float* adj0 = (const float*)d_in[0];
    const float* adj1 = (const float*)d_in[1];
    const float* adj2 = (const float*)d_in[2];
    const float* adj3 = (const float*)d_in[3];
    // d_in[4] = batch_idxes (unused by the reference)
    const float* feat_opes       = (const float*)d_in[5];
    const float* feat_mas        = (const float*)d_in[6];
    const float* feat_buf        = (const float*)d_in[7];
    const float* feat_arc_ma_in  = (const float*)d_in[8];
    const float* feat_arc_buf_in = (const float*)d_in[9];
    const float* feat_arc_ma_out = (const float*)d_in[10];
    const float* feat_arc_buf_out= (const float*)d_in[11];
    const float* W_ope    = (const float*)d_in[12];
    const float* W_mas    = (const float*)d_in[13];
    const float* W_buf    = (const float*)d_in[14];
    const float* W_arc_in = (const float*)d_in[15];
    const float* W_arc_out= (const float*)d_in[16];
    const float* attn_ope = (const float*)d_in[17];
    const float* attn_mas = (const float*)d_in[18];
    const float* attn_arc = (const float*)d_in[19];

    float* ws  = (float*)d_ws;
    float* out = (float*)d_out;

    if (ws_size < (size_t)(WS_PART + GRID*NPQ)*sizeof(float)) return;

    // 64 e_ope + 8 p_node + 1 w_arc + 16 mask-pack blocks
    k_pre<<<89, 256, 0, stream>>>(adj0, adj1, adj2, adj3,
                                  feat_opes, feat_mas, feat_buf,
                                  W_ope, W_mas, W_buf, W_arc_in, W_arc_out,
                                  attn_ope, attn_mas, attn_arc, ws);

    k_main<<<GRID, 256, 0, stream>>>(feat_opes,
                                     feat_arc_ma_in, feat_arc_buf_in,
                                     feat_arc_ma_out, feat_arc_buf_out, ws);

    k_redfin<<<2*B_*2, 256, 0, stream>>>(W_ope, W_arc_in, W_arc_out, ws, out);
}

// Round 8
// 204.307 us; speedup vs baseline: 1.9990x; 1.0111x over previous
//
#include <hip/hip_runtime.h>
#include <math.h>

#define B_   16
#define O_   1024
#define M_   64
#define C_   32
#define INO  16
#define INA  8
#define SLOPE 0.2f

// per-block partials: 25 parity-split fields x 64 lanes
#define NPQ   1600
#define NCH   2              // sequential o-chunks (of 32) per block
#define NSG   16             // o super-groups: 16 x 64 rows
#define GRID  (2*B_*2*NSG)   // 1024 blocks = 4/CU = 16 waves/CU (VGPR-128 cap)

// workspace layout (float offsets)
#define WS_EOPE   0
#define WS_ENODE  (WS_EOPE + B_*O_)              // 16384
#define WS_PNODE  (WS_ENODE + 2*B_*M_)           // 18432
#define WS_WARC   (WS_PNODE + 2*B_*M_*C_)        // 83968
#define WS_MASK   (WS_WARC + 16)                 // 83984 (8192 floats = 32 KB packed adj bits)
#define WS_PART   (WS_MASK + 8192)               // 92176 (GRID*NPQ floats = 6.5 MB)

typedef float f32x4 __attribute__((ext_vector_type(4)));

__device__ inline float rfl(float x) {
    return __int_as_float(__builtin_amdgcn_readfirstlane(__float_as_int(x)));
}

// non-temporal (no-allocate) 16B load. r6: first lever in 7 rounds that moved
// k_main (52 -> ~38us) -- bypasses the 2.7 TB/s MALL-mixed service path.
// r7: deeper MLP changed nothing => NT path itself is service-limited ~3.5 TB/s.
__device__ __forceinline__ f32x4 ntload4(const float* p) {
    return __builtin_nontemporal_load((const f32x4*)p);
}
__device__ __forceinline__ void ntstore(float* p, float v) {
    __builtin_nontemporal_store(v, p);
}

// ---------------- kernel 0: precompute (e_ope, p_node/e_node, w_arc, adj bitmasks) ----------------
// Mask packing rewritten: coalesced float4 row loads + shfl_xor bit-transpose
// (old version: 32 scalar stride-256B loads/thread ~ 16x over-fetch).
__global__ void k_pre(const float* __restrict__ adj0, const float* __restrict__ adj1,
                      const float* __restrict__ adj2, const float* __restrict__ adj3,
                      const float* __restrict__ feat_opes,
                      const float* __restrict__ feat_mas,
                      const float* __restrict__ feat_buf,
                      const float* __restrict__ W_ope,
                      const float* __restrict__ W_mas,
                      const float* __restrict__ W_buf,
                      const float* __restrict__ W_arc_in,
                      const float* __restrict__ W_arc_out,
                      const float* __restrict__ attn_ope,
                      const float* __restrict__ attn_mas,
                      const float* __restrict__ attn_arc,
                      float* __restrict__ ws) {
    int tid = threadIdx.x;
    int bid = blockIdx.x;
    if (bid < 64) {
        // e_ope[b,o] = feat_opes[b,o,:] . (W_ope @ attn_ope)
        __shared__ float wo[INO];
        if (tid < INO) {
            float s = 0.f;
            for (int c = 0; c < C_; ++c) s += W_ope[tid*C_ + c]*attn_ope[c];
            wo[tid] = s;
        }
        __syncthreads();
        int idx = bid*256 + tid;                 // [0, 16384)
        const float* f = feat_opes + idx*INO;
        float s = 0.f;
#pragma unroll
        for (int j = 0; j < INO; ++j) s += f[j]*wo[j];
        ws[WS_EOPE + idx] = s;
    } else if (bid < 72) {
        // p_node / e_node for both branches
        int idx = (bid - 64)*256 + tid;          // [0, 2048)
        int br  = idx >> 10;
        int rem = idx & 1023;
        const float* f = (br == 0 ? feat_mas : feat_buf) + rem*INA;
        const float* W = (br == 0 ? W_mas : W_buf);
        float f8[INA];
#pragma unroll
        for (int k = 0; k < INA; ++k) f8[k] = f[k];
        float e = 0.f;
        float* pn = ws + WS_PNODE + idx*C_;
        for (int c = 0; c < C_; ++c) {
            float s = 0.f;
#pragma unroll
            for (int k = 0; k < INA; ++k) s += f8[k]*W[k*C_ + c];
            pn[c] = s;
            e += s*attn_mas[c];
        }
        ws[WS_ENODE + idx] = e;
    } else if (bid == 72) {
        // w_arc_in/out 8-vectors: W_arc @ attn_arc
        if (tid < 16) {
            const float* W = (tid < 8) ? W_arc_in : W_arc_out;
            int k = tid & 7;
            float s = 0.f;
            for (int c = 0; c < C_; ++c) s += W[k*C_ + c]*attn_arc[c];
            ws[WS_WARC + tid] = s;
        }
    } else {
        // bid 73..76: coalesced mask packing, one block per adjacency matrix.
        // Wave lane l = (oo = l>>4, mq = l&15): one instruction loads 4 full
        // o-rows (64 lanes x 16B = 1KB, fully dense). Bits transposed to
        // m-major via 2 shfl_xor OR-reduces over the oo axis.
        int q  = bid - 73;                  // 0:adj0(in,br0) 1:adj1(out,br0) 2:adj2 3:adj3
        const float* A = (q == 0) ? adj0 : (q == 1) ? adj1 : (q == 2) ? adj2 : adj3;
        int br = q >> 1;
        int l  = tid & 63;
        int y  = tid >> 6;
        int mq = l & 15;
        int oo = l >> 4;
        unsigned* mp = (unsigned*)(ws + WS_MASK);
        for (int t = 0; t < 8; ++t) {
            int j4 = y*8 + t;               // o-group [j4*32, j4*32+32)
            unsigned mk0 = 0u, mk1 = 0u, mk2 = 0u, mk3 = 0u;
#pragma unroll
            for (int g2 = 0; g2 < 8; ++g2) {
                int o = j4*32 + g2*4 + oo;
                float4 v = *(const float4*)(A + o*M_ + mq*4);
                unsigned bit = 1u << (g2*4 + oo);
                if (v.x == 1.0f) mk0 |= bit;
                if (v.y == 1.0f) mk1 |= bit;
                if (v.z == 1.0f) mk2 |= bit;
                if (v.w == 1.0f) mk3 |= bit;
            }
            mk0 |= (unsigned)__shfl_xor((int)mk0, 16); mk0 |= (unsigned)__shfl_xor((int)mk0, 32);
            mk1 |= (unsigned)__shfl_xor((int)mk1, 16); mk1 |= (unsigned)__shfl_xor((int)mk1, 32);
            mk2 |= (unsigned)__shfl_xor((int)mk2, 16); mk2 |= (unsigned)__shfl_xor((int)mk2, 32);
            mk3 |= (unsigned)__shfl_xor((int)mk3, 16); mk3 |= (unsigned)__shfl_xor((int)mk3, 32);
            if (oo == 0) {
                int base = (br*M_ + mq*4)*64 + (q & 1)*32 + j4;
                mp[base]        = mk0;
                mp[base + 64]   = mk1;
                mp[base + 128]  = mk2;
                mp[base + 192]  = mk3;
            }
        }
    }
}

// ---------------- kernel A: main streaming pass (hybrid NT/cached split) ----------------
// r7 body; ONE change: the two arc streams are split across service paths.
// fin -> NT (DRAM-direct), fout -> cached (MALL path). Measured pure rates:
// all-cached 2.7 TB/s (r0-r5), all-NT 3.5 TB/s (r6-r7). If the paths
// partially parallelize (separate queues to the fabric; MALL retains the
// 67MB cached half across the fill, as r0-r5's FETCH=67MB showed), delivered
// BW rises toward their concurrent sum.
__global__ __launch_bounds__(256) void k_main(
        const float* __restrict__ feat_opes,
        const float* __restrict__ fin_ma,  const float* __restrict__ fin_buf,
        const float* __restrict__ fout_ma, const float* __restrict__ fout_buf,
        float* __restrict__ ws) {
    int tid = threadIdx.x;
    int l   = tid & 63;
    int p   = l & 1;                                  // k-half / field parity
    int y   = __builtin_amdgcn_readfirstlane(tid >> 6);

    int bid = blockIdx.x;                 // [0, 1024)
    int sg  = bid & (NSG - 1);            // 64-row super-group
    int h   = (bid >> 4) & 1;             // m-half
    int b   = (bid >> 5) & (B_ - 1);
    int br  = bid >> 9;

    int m   = h*32 + (l >> 1);

    const float* fin   = br ? fin_buf  : fin_ma;
    const float* fout  = br ? fout_buf : fout_ma;

    // reduction-only LDS (19.2 KB): 3 waves x 25 fields x 64 lanes
    __shared__ float smem[4800];

    float e_node_m = ws[WS_ENODE + (br*B_ + b)*M_ + m];

    // per-parity 4-element weight slices
    const float* wv = ws + WS_WARC + 4*p;
    float wiA = wv[0], wiB = wv[1], wiC = wv[2], wiD = wv[3];
    float woA = wv[8], woB = wv[9], woC = wv[10], woD = wv[11];

    // packed adjacency for this block's 64-row span: one uint2 per matrix
    const uint2* mp2 = (const uint2*)((const unsigned*)(ws + WS_MASK) + (br*M_ + m)*64);
    uint2 mA = mp2[sg];
    uint2 mB = mp2[16 + sg];

    const float* pib = fin  + (size_t)b*O_*512 + h*256 + l*4;
    const float* pob = fout + (size_t)b*O_*512 + h*256 + l*4;

    int o0b = sg*64 + y*8;                // this wave's chunk-0 row base
    const float* pi = pib + (size_t)o0b*512;
    const float* po = pob + (size_t)o0b*512;

    float ai0 = 0.f, ai1 = 0.f, ai2 = 0.f, ai3 = 0.f;
    float s0 = 0.f, s1 = 0.f, s2 = 0.f, s3 = 0.f;
    float lsum = 0.f;
    float aoi[8], aoo[8];
#pragma unroll
    for (int j = 0; j < 8; ++j) { aoi[j] = 0.f; aoo[j] = 0.f; }

    // hoisted 4-deep rotating pipeline (lives across chunks):
    // bi = NT stream (fin), bu = cached stream (fout)
    f32x4 bi[4], bu[4];
#pragma unroll
    for (int q = 0; q < 4; ++q) {
        bi[q] = ntload4(pi + q*512);
        bu[q] = *(const f32x4*)(po + q*512);
    }

#pragma unroll
    for (int ch = 0; ch < NCH; ++ch) {
        int o0 = o0b + ch*32;
        const float* pc = pi + (size_t)ch*32*512;   // current chunk row-0 addr
        const float* uc = po + (size_t)ch*32*512;

        // wave-uniform e_ope -> SGPRs (64 KB table, L2-hot)
        const float* e_ope = ws + WS_EOPE + b*O_ + o0;
        float eo[8];
#pragma unroll
        for (int i = 0; i < 8; ++i) eo[i] = rfl(e_ope[i]);

        unsigned wAw = ch ? mA.y : mA.x;
        unsigned wBw = ch ? mB.y : mB.x;
        unsigned amA = (wAw >> (y*8)) & 0xffu;
        unsigned amB = (wBw >> (y*8)) & 0xffu;

        float wiv[8], wov[8];

#pragma unroll
        for (int it = 0; it < 8; ++it) {
            const int sl = it & 3;
            f32x4 i4 = bi[sl], u4 = bu[sl];
            if (it < 4) {
                // back half of this chunk
                bi[sl] = ntload4(pc + (it+4)*512);
                bu[sl] = *(const f32x4*)(uc + (it+4)*512);
            } else if (ch + 1 < NCH) {
                // front half of the NEXT chunk (rows +32..+35)
                bi[sl] = ntload4(pc + (32 + it - 4)*512);
                bu[sl] = *(const f32x4*)(uc + (32 + it - 4)*512);
            }
            float einp = i4.x*wiA + i4.y*wiB + i4.z*wiC + i4.w*wiD;
            float eutp = u4.x*woA + u4.y*woB + u4.z*woC + u4.w*woD;
            float ein = einp + __shfl_xor(einp, 1);
            float eut = eutp + __shfl_xor(eutp, 1);
            float bs = eo[it] + e_node_m;
            float si = bs + ein;  si = si > 0.f ? si : SLOPE*si;
            float so = bs + eut;  so = so > 0.f ? so : SLOPE*so;
            float wgi = ((amA >> it) & 1u) ? __expf(si) : 0.f;
            float wgo = ((amB >> it) & 1u) ? __expf(so) : 0.f;
            wiv[it] = wgi; wov[it] = wgo;
            ai0 += wgi*i4.x; ai1 += wgi*i4.y; ai2 += wgi*i4.z; ai3 += wgi*i4.w;
            s0  += u4.x;     s1  += u4.y;     s2  += u4.z;     s3  += u4.w;
            lsum += p ? wgo : wgi;
        }

        // deferred feat_opes-weighted sums (reused rows -> cached loads);
        // runs while the next chunk's loads are in flight
        const float* fo = feat_opes + (size_t)(b*O_ + o0)*INO + p*8;
#pragma unroll
        for (int it = 0; it < 8; ++it) {
            float4 f0 = *(const float4*)(fo + it*INO);
            float4 f1 = *(const float4*)(fo + it*INO + 4);
            float wgi = wiv[it], wgo = wov[it];
            aoi[0] += wgi*f0.x; aoi[1] += wgi*f0.y; aoi[2] += wgi*f0.z; aoi[3] += wgi*f0.w;
            aoi[4] += wgi*f1.x; aoi[5] += wgi*f1.y; aoi[6] += wgi*f1.z; aoi[7] += wgi*f1.w;
            aoo[0] += wgo*f0.x; aoo[1] += wgo*f0.y; aoo[2] += wgo*f0.z; aoo[3] += wgo*f0.w;
            aoo[4] += wgo*f1.x; aoo[5] += wgo*f1.y; aoo[6] += wgo*f1.z; aoo[7] += wgo*f1.w;
        }
    }

    // pack parity-split state vector (25 fields per lane)
    float v[25];
    v[0] = lsum;
    v[1] = ai0; v[2] = ai1; v[3] = ai2; v[4] = ai3;
#pragma unroll
    for (int j = 0; j < 8; ++j) { v[5+j] = aoi[j]; v[13+j] = aoo[j]; }
    v[21] = s0; v[22] = s1; v[23] = s2; v[24] = s3;

    // intra-block additive reduction (waves 1..3 -> wave 0)
    __syncthreads();
    if (y > 0) {
#pragma unroll
        for (int q = 0; q < 25; ++q) smem[(y-1)*1600 + q*64 + l] = v[q];
    }
    __syncthreads();
    if (y == 0) {
#pragma unroll
        for (int q = 0; q < 25; ++q)
            v[q] += smem[q*64 + l] + smem[1600 + q*64 + l] + smem[3200 + q*64 + l];
        // write-once partials -> non-temporal coalesced stores
        float* pp = ws + WS_PART + (size_t)bid*NPQ;
#pragma unroll
        for (int q = 0; q < 25; ++q)
            ntstore(pp + q*64 + l, v[q]);
    }
}

// ---------------- kernel B: fused 16-way reduce + epilogue ----------------
__global__ __launch_bounds__(256) void k_redfin(
        const float* __restrict__ W_ope,
        const float* __restrict__ W_arc_in,
        const float* __restrict__ W_arc_out,
        const float* __restrict__ ws,
        float* __restrict__ out) {
    int tid = threadIdx.x;
    int bid = blockIdx.x;           // [0,64)
    int h  = bid & 1;
    int b  = (bid >> 1) & (B_ - 1);
    int br = bid >> 5;

    __shared__ float sW[1024];      // [0..511]=W_ope, [512..767]=W_arc_in, [768..1023]=W_arc_out
    __shared__ float red2[25*64];   // reduced partials for this (br,b,h)
    __shared__ float cinv[32][3];   // per-column inv_i, inv_o, akk

    for (int i = tid; i < 512; i += 256) sW[i] = W_ope[i];
    if (tid < 256) { sW[512 + tid] = W_arc_in[tid]; sW[768 + tid] = W_arc_out[tid]; }

    // 16-way reduction over the group's super-group blocks (dense 256B runs)
    const float* part = ws + WS_PART;
    int pbase = br*512 + b*32 + h*16;    // k_main bid of sg=0
    for (int ot = tid; ot < 25*64; ot += 256) {
        float s = 0.f;
#pragma unroll
        for (int c2 = 0; c2 < NSG; ++c2)
            s += part[(size_t)(pbase + c2)*NPQ + ot];
        red2[ot] = s;
    }
    __syncthreads();

    // per-column scalars
    if (tid < 32) {
        int j = tid;
        int col = (br*B_ + b)*M_ + h*32 + j;
        float li = red2[2*j];            // field 0 @ even lane = l_in
        float lo = red2[2*j + 1];        // field 0 @ odd lane  = l_out
        float en  = ws[WS_ENODE + col];
        float ekk = 2.f*en; ekk = ekk > 0.f ? ekk : SLOPE*ekk;
        float wkk = __expf(ekk);
        float inv_i = 1.f/(li + wkk);
        float inv_o = 1.f/(lo + wkk);
        cinv[j][0] = inv_i;
        cinv[j][1] = inv_o;
        cinv[j][2] = wkk*inv_i + wkk*inv_o;
    }
    __syncthreads();

    // epilogue: 32 columns x 32 outputs; thread -> (j, 4 c's)
    int j  = tid >> 3;
    int c0 = tid & 7;
    int col = (br*B_ + b)*M_ + h*32 + j;
    int l0 = 2*j, l1 = 2*j + 1;

    float vai[8], vsao[8], vaoi[16], vaoo[16];
#pragma unroll
    for (int k = 0; k < 4; ++k) {
        vai[k]    = red2[(1+k)*64  + l0];
        vai[4+k]  = red2[(1+k)*64  + l1];
        vsao[k]   = red2[(21+k)*64 + l0];
        vsao[4+k] = red2[(21+k)*64 + l1];
    }
#pragma unroll
    for (int k = 0; k < 8; ++k) {
        vaoi[k]   = red2[(5+k)*64  + l0];
        vaoi[8+k] = red2[(5+k)*64  + l1];
        vaoo[k]   = red2[(13+k)*64 + l0];
        vaoo[8+k] = red2[(13+k)*64 + l1];
    }

    float inv_i = cinv[j][0], inv_o = cinv[j][1], akk = cinv[j][2];
    const float* pn = ws + WS_PNODE + (size_t)col*C_;
    float* op = out + (size_t)col*C_;

#pragma unroll
    for (int k = 0; k < 4; ++k) {
        int c = c0 + 8*k;
        float s_ai = 0.f, s_oi = 0.f, s_ao = 0.f, s_oo = 0.f;
#pragma unroll
        for (int q = 0; q < 8; ++q) {
            s_ai += vai[q] *sW[512 + q*C_ + c];
            s_ao += vsao[q]*sW[768 + q*C_ + c];
        }
#pragma unroll
        for (int q = 0; q < 16; ++q) {
            float wv = sW[q*C_ + c];
            s_oi += vaoi[q]*wv;
            s_oo += vaoo[q]*wv;
        }
        float x = (s_ai + s_oi)*inv_i + s_ao + s_oo*inv_o + pn[c]*akk;
        op[c] = 1.f/(1.f + __expf(-x));
    }
}

extern "C" void kernel_launch(void* const* d_in, const int* in_sizes, int n_in,
                              void* d_out, int out_size, void* d_ws, size_t ws_size,
                              hipStream_t stream) {
    const float* adj0 = (const float*)d_in[0];
    const float* adj1 = (const float*)d_in[1];
    const float* adj2 = (const float*)d_in[2];
    const float* adj3 = (const float*)d_in[3];
    // d_in[4] = batch_idxes (unused by the reference)
    const float* feat_opes       = (const float*)d_in[5];
    const float* feat_mas        = (const float*)d_in[6];
    const float* feat_buf        = (const float*)d_in[7];
    const float* feat_arc_ma_in  = (const float*)d_in[8];
    const float* feat_arc_buf_in = (const float*)d_in[9];
    const float* feat_arc_ma_out = (const float*)d_in[10];
    const float* feat_arc_buf_out= (const float*)d_in[11];
    const float* W_ope    = (const float*)d_in[12];
    const float* W_mas    = (const float*)d_in[13];
    const float* W_buf    = (const float*)d_in[14];
    const float* W_arc_in = (const float*)d_in[15];
    const float* W_arc_out= (const float*)d_in[16];
    const float* attn_ope = (const float*)d_in[17];
    const float* attn_mas = (const float*)d_in[18];
    const float* attn_arc = (const float*)d_in[19];

    float* ws  = (float*)d_ws;
    float* out = (float*)d_out;

    if (ws_size < (size_t)(WS_PART + GRID*NPQ)*sizeof(float)) return;

    // 64 e_ope + 8 p_node + 1 w_arc + 4 mask-pack blocks
    k_pre<<<77, 256, 0, stream>>>(adj0, adj1, adj2, adj3,
                                  feat_opes, feat_mas, feat_buf,
                                  W_ope, W_mas, W_buf, W_arc_in, W_arc_out,
                                  attn_ope, attn_mas, attn_arc, ws);

    k_main<<<GRID, 256, 0, stream>>>(feat_opes,
                                     feat_arc_ma_in, feat_arc_buf_in,
                                     feat_arc_ma_out, feat_arc_buf_out, ws);

    k_redfin<<<2*B_*2, 256, 0, stream>>>(W_ope, W_arc_in, W_arc_out, ws, out);
}